// Round 1
// baseline (563.535 us; speedup 1.0000x reference)
//
#include <hip/hip_runtime.h>
#include <math.h>

namespace {

constexpr int NI  = 8;
constexpr int NC  = 32;
constexpr int NH  = 480;
constexpr int NW  = 480;
constexpr int NPTS = 64 * 64 * 64;          // 262144
constexpr int NOUTC = NC + 5;               // 37
constexpr long long HW = (long long)NH * NW;

__global__ __launch_bounds__(256)
void smear_kernel(const float* __restrict__ coords,   // (3, N)
                  const float* __restrict__ images,   // (I, C, H, W)
                  const float* __restrict__ trans,    // (I, 3, 4)
                  const float* __restrict__ tcw,      // (I, 4, 4)
                  float* __restrict__ out)            // (I, 37, N)
{
#pragma clang fp contract(off)
    __shared__ float s_tr[NI][12];   // transformations
    __shared__ float s_t2[NI][4];    // T_cw row 2 (depth row)
    __shared__ float s_cam[NI][3];   // camera centers

    const int tid = threadIdx.x;
    if (tid < NI * 12) s_tr[tid / 12][tid % 12] = trans[tid];
    if (tid < NI * 4)  s_t2[tid >> 2][tid & 3]  = tcw[(tid >> 2) * 16 + 8 + (tid & 3)];
    if (tid < NI * 3) {
        const int i = tid / 3, l = tid - i * 3;
        const float* T = tcw + i * 16;
        // cam_center[l] = -(R[0][l]*t[0] + R[1][l]*t[1] + R[2][l]*t[2]), sequential sum
        float cc = T[0 + l] * T[3] + T[4 + l] * T[7];
        cc = cc + T[8 + l] * T[11];
        s_cam[i][l] = -cc;
    }
    __syncthreads();

    const int n = blockIdx.x * 256 + tid;
    const float x  = coords[n];
    const float y  = coords[NPTS + n];
    const float zc = coords[2 * NPTS + n];

    for (int i = 0; i < NI; ++i) {
        const float* tr = s_tr[i];
        // pix = trans[i] @ [x,y,z,1]  -- sequential sum, no fma (match numpy)
        const float p0 = ((tr[0] * x + tr[1] * y) + tr[2]  * zc) + tr[3];
        const float p1 = ((tr[4] * x + tr[5] * y) + tr[6]  * zc) + tr[7];
        const float p2 = ((tr[8] * x + tr[9] * y) + tr[10] * zc) + tr[11];

        const float zs = (fabsf(p2) < 1e-8f) ? 1e-8f : p2;
        const float u = p0 / zs;
        const float v = p1 / zs;
        const bool valid = (p2 > 0.0f) && (u >= 0.0f) && (u <= (float)(NW - 1))
                                       && (v >= 0.0f) && (v <= (float)(NH - 1));
        // np.round == round-half-even == rintf
        const float ur = fminf(fmaxf(rintf(u), 0.0f), (float)(NW - 1));
        const float vr = fminf(fmaxf(rintf(v), 0.0f), (float)(NH - 1));
        const int ui = (int)ur;
        const int vi = (int)vr;
        const float validity = valid ? 1.0f : 0.0f;

        const float* t2 = s_t2[i];
        const float depth = ((t2[0] * x + t2[1] * y) + t2[2] * zc) + t2[3];

        const float dx = x  - s_cam[i][0];
        const float dy = y  - s_cam[i][1];
        const float dz = zc - s_cam[i][2];
        float nrm = sqrtf((dx * dx + dy * dy) + dz * dz);
        nrm = fmaxf(nrm, 1e-8f);

        float* ob = out + ((long long)i * NOUTC) * NPTS + n;

        if (valid) {
            const float* ip = images + ((long long)i * NC) * HW + (long long)vi * NW + ui;
            #pragma unroll
            for (int c = 0; c < NC; ++c)
                __builtin_nontemporal_store(ip[c * HW], ob + (long long)c * NPTS);
        } else {
            #pragma unroll
            for (int c = 0; c < NC; ++c)
                __builtin_nontemporal_store(0.0f, ob + (long long)c * NPTS);
        }
        __builtin_nontemporal_store(depth,     ob + (long long)(NC + 0) * NPTS);
        __builtin_nontemporal_store(validity,  ob + (long long)(NC + 1) * NPTS);
        __builtin_nontemporal_store(dx / nrm,  ob + (long long)(NC + 2) * NPTS);
        __builtin_nontemporal_store(dy / nrm,  ob + (long long)(NC + 3) * NPTS);
        __builtin_nontemporal_store(dz / nrm,  ob + (long long)(NC + 4) * NPTS);
    }
}

} // namespace

extern "C" void kernel_launch(void* const* d_in, const int* in_sizes, int n_in,
                              void* d_out, int out_size, void* d_ws, size_t ws_size,
                              hipStream_t stream)
{
    const float* coords = (const float*)d_in[0];
    const float* images = (const float*)d_in[1];
    const float* trans  = (const float*)d_in[2];
    const float* tcw    = (const float*)d_in[3];
    float* out = (float*)d_out;

    smear_kernel<<<dim3(NPTS / 256), dim3(256), 0, stream>>>(coords, images, trans, tcw, out);
}

// Round 3
// 446.808 us; speedup vs baseline: 1.2612x; 1.2612x over previous
//
#include <hip/hip_runtime.h>
#include <math.h>

namespace {

typedef float f32x4 __attribute__((ext_vector_type(4)));

constexpr int NI   = 8;
constexpr int NC   = 32;
constexpr int NH   = 480;
constexpr int NW   = 480;
constexpr int NPTS = 64 * 64 * 64;          // 262144
constexpr int NOUTC = NC + 5;               // 37
constexpr long long HW = (long long)NH * NW;
constexpr int PPT = 4;                      // points per thread (16B stores)
constexpr int TPB = 256;

__global__ __launch_bounds__(TPB)
void smear_kernel(const float* __restrict__ coords,   // (3, N)
                  const float* __restrict__ images,   // (I, C, H, W)
                  const float* __restrict__ trans,    // (I, 3, 4)
                  const float* __restrict__ tcw,      // (I, 4, 4)
                  float* __restrict__ out)            // (I, 37, N)
{
#pragma clang fp contract(off)
    const int img = blockIdx.y;

    __shared__ float s_tr[12];   // transformations[img]
    __shared__ float s_t2[4];    // T_cw[img] row 2 (depth row)
    __shared__ float s_cam[3];   // camera center

    const int tid = threadIdx.x;
    if (tid < 12) s_tr[tid] = trans[img * 12 + tid];
    if (tid < 4)  s_t2[tid] = tcw[img * 16 + 8 + tid];
    if (tid < 3) {
        const float* T = tcw + img * 16;
        // cam_center[l] = -(R[0][l]*t[0] + R[1][l]*t[1] + R[2][l]*t[2]), sequential
        float cc = T[0 + tid] * T[3] + T[4 + tid] * T[7];
        cc = cc + T[8 + tid] * T[11];
        s_cam[tid] = -cc;
    }
    __syncthreads();

    const int n0 = (blockIdx.x * TPB + tid) * PPT;
    const f32x4 xv = *(const f32x4*)(coords + n0);
    const f32x4 yv = *(const f32x4*)(coords + NPTS + n0);
    const f32x4 zv = *(const f32x4*)(coords + 2 * NPTS + n0);

    // --- projection: offsets + validity (no divergence downstream) ---
    int   off[4];
    float validity[4];
    #pragma unroll
    for (int k = 0; k < PPT; ++k) {
        const float x = xv[k], y = yv[k], z = zv[k];
        const float p0 = ((s_tr[0] * x + s_tr[1] * y) + s_tr[2]  * z) + s_tr[3];
        const float p1 = ((s_tr[4] * x + s_tr[5] * y) + s_tr[6]  * z) + s_tr[7];
        const float p2 = ((s_tr[8] * x + s_tr[9] * y) + s_tr[10] * z) + s_tr[11];
        const float zsafe = (fabsf(p2) < 1e-8f) ? 1e-8f : p2;
        const float u = p0 / zsafe;
        const float v = p1 / zsafe;
        const bool valid = (p2 > 0.0f) && (u >= 0.0f) && (u <= (float)(NW - 1))
                                       && (v >= 0.0f) && (v <= (float)(NH - 1));
        const int ui = (int)fminf(fmaxf(rintf(u), 0.0f), (float)(NW - 1));
        const int vi = (int)fminf(fmaxf(rintf(v), 0.0f), (float)(NH - 1));
        // invalid lanes all read pixel 0 (one hot line), result multiplied by 0
        off[k]      = valid ? (vi * NW + ui) : 0;
        validity[k] = valid ? 1.0f : 0.0f;
    }

    // --- feature gather + full-exec 16B nt stores ---
    const float* ib = images + (long long)img * NC * HW;
    float*       ob = out    + (long long)img * NOUTC * NPTS + n0;
    #pragma unroll
    for (int c = 0; c < NC; ++c) {
        const float* ip = ib + (long long)c * HW;
        f32x4 f;
        f[0] = ip[off[0]] * validity[0];
        f[1] = ip[off[1]] * validity[1];
        f[2] = ip[off[2]] * validity[2];
        f[3] = ip[off[3]] * validity[3];
        __builtin_nontemporal_store(f, (f32x4*)(ob + (long long)c * NPTS));
    }

    // --- depth, validity, view-dir channels ---
    f32x4 d4, a4, x4, y4, z4;
    #pragma unroll
    for (int k = 0; k < PPT; ++k) {
        const float x = xv[k], y = yv[k], z = zv[k];
        d4[k] = ((s_t2[0] * x + s_t2[1] * y) + s_t2[2] * z) + s_t2[3];
        a4[k] = validity[k];
        const float dx = x - s_cam[0];
        const float dy = y - s_cam[1];
        const float dz = z - s_cam[2];
        float nrm = sqrtf((dx * dx + dy * dy) + dz * dz);
        nrm = fmaxf(nrm, 1e-8f);
        x4[k] = dx / nrm;
        y4[k] = dy / nrm;
        z4[k] = dz / nrm;
    }
    __builtin_nontemporal_store(d4, (f32x4*)(ob + (long long)(NC + 0) * NPTS));
    __builtin_nontemporal_store(a4, (f32x4*)(ob + (long long)(NC + 1) * NPTS));
    __builtin_nontemporal_store(x4, (f32x4*)(ob + (long long)(NC + 2) * NPTS));
    __builtin_nontemporal_store(y4, (f32x4*)(ob + (long long)(NC + 3) * NPTS));
    __builtin_nontemporal_store(z4, (f32x4*)(ob + (long long)(NC + 4) * NPTS));
}

} // namespace

extern "C" void kernel_launch(void* const* d_in, const int* in_sizes, int n_in,
                              void* d_out, int out_size, void* d_ws, size_t ws_size,
                              hipStream_t stream)
{
    const float* coords = (const float*)d_in[0];
    const float* images = (const float*)d_in[1];
    const float* trans  = (const float*)d_in[2];
    const float* tcw    = (const float*)d_in[3];
    float* out = (float*)d_out;

    dim3 grid(NPTS / (TPB * PPT), NI);
    smear_kernel<<<grid, dim3(TPB), 0, stream>>>(coords, images, trans, tcw, out);
}